// Round 2
// baseline (711.144 us; speedup 1.0000x reference)
//
#include <hip/hip_runtime.h>

// ATTConv: T=3, N=4 (3 neighbors + self), D=128, B=100000.
// score[t,n,b] = leakyrelu( e[n]·w_e[t] + e[3]·w_h[t] + att_b[t] ),  e[3]=h_center
// attn = softmax over n; out[t,b,:] = sum_n attn[n] * e[n]
//
// One 32-lane half-wave per (t,b) row; lane holds float4 of each of 4 vectors.
// Per-lane fold: u[n] = e[n]·w_e + e[3]·w_h  -> only 4 values butterfly-reduced
// via ds_swizzle (xor 16,8,4,2,1 stays within each 32-lane group).
// Memory-bound: 615 MB fetch + 154 MB write -> ~122 us floor at 6.3 TB/s.

#define TT 3
#define NN 4
#define DD 128
#define NEG_SLOPE 0.01f

// ds_swizzle BitMode: offset = (xor<<10)|(or<<5)|and, and=0x1F keeps it in the
// 32-lane group. xor 1,2,4,8,16 -> 0x041F,0x081F,0x101F,0x201F,0x401F.
#define SWADD4(pat)                                                              \
    u0 += __int_as_float(__builtin_amdgcn_ds_swizzle(__float_as_int(u0), pat)); \
    u1 += __int_as_float(__builtin_amdgcn_ds_swizzle(__float_as_int(u1), pat)); \
    u2 += __int_as_float(__builtin_amdgcn_ds_swizzle(__float_as_int(u2), pat)); \
    u3 += __int_as_float(__builtin_amdgcn_ds_swizzle(__float_as_int(u3), pat));

__global__ __launch_bounds__(256) void attconv_kernel(
    const float* __restrict__ h_center,  // (T,B,D)
    const float* __restrict__ h_neigh,   // (T,T,B,D)
    const float* __restrict__ att_w,     // (T,2D)
    const float* __restrict__ att_b,     // (T,)
    float* __restrict__ out,             // (T,B,D)
    int B)
{
    const int t    = blockIdx.y;                       // 0..2
    const int lane = threadIdx.x & 31;                 // float4 index within row
    const int b    = blockIdx.x * 8 + (threadIdx.x >> 5);
    if (b >= B) return;

    // per-head weights (uniform per block's t; each lane takes its 4 floats)
    const float4* wv = (const float4*)(att_w + (size_t)t * 2 * DD);
    const float4 wh = wv[lane];
    const float4 we = wv[32 + lane];

    // load 4 emd vectors — all issued before use for max outstanding loads
    const float4* cen = (const float4*)(h_center + ((size_t)t * B + b) * DD);
    const float4* ng0 = (const float4*)(h_neigh + (((size_t)t * TT + 0) * B + b) * DD);
    const float4* ng1 = (const float4*)(h_neigh + (((size_t)t * TT + 1) * B + b) * DD);
    const float4* ng2 = (const float4*)(h_neigh + (((size_t)t * TT + 2) * B + b) * DD);
    float4 e0 = ng0[lane];
    float4 e1 = ng1[lane];
    float4 e2 = ng2[lane];
    float4 e3 = cen[lane];

    // per-lane partials: u[n] = e[n]·w_e + e[3]·w_h  (s4 folded before reduce)
    float s4p = fmaf(e3.x, wh.x, fmaf(e3.y, wh.y, fmaf(e3.z, wh.z, e3.w * wh.w)));
    float u0 = fmaf(e0.x, we.x, fmaf(e0.y, we.y, fmaf(e0.z, we.z, fmaf(e0.w, we.w, s4p))));
    float u1 = fmaf(e1.x, we.x, fmaf(e1.y, we.y, fmaf(e1.z, we.z, fmaf(e1.w, we.w, s4p))));
    float u2 = fmaf(e2.x, we.x, fmaf(e2.y, we.y, fmaf(e2.z, we.z, fmaf(e2.w, we.w, s4p))));
    float u3 = fmaf(e3.x, we.x, fmaf(e3.y, we.y, fmaf(e3.z, we.z, fmaf(e3.w, we.w, s4p))));

    // butterfly reduce 4 values across the 32-lane group (20 ds_swizzle)
    SWADD4(0x401F)  // xor 16
    SWADD4(0x201F)  // xor 8
    SWADD4(0x101F)  // xor 4
    SWADD4(0x081F)  // xor 2
    SWADD4(0x041F)  // xor 1

    // scores + leaky relu + softmax over 4 (redundant per lane — cheap)
    const float bias = att_b[t];
    float x0 = u0 + bias; x0 = (x0 >= 0.f) ? x0 : NEG_SLOPE * x0;
    float x1 = u1 + bias; x1 = (x1 >= 0.f) ? x1 : NEG_SLOPE * x1;
    float x2 = u2 + bias; x2 = (x2 >= 0.f) ? x2 : NEG_SLOPE * x2;
    float x3 = u3 + bias; x3 = (x3 >= 0.f) ? x3 : NEG_SLOPE * x3;
    float m = fmaxf(fmaxf(x0, x1), fmaxf(x2, x3));
    x0 = __expf(x0 - m);
    x1 = __expf(x1 - m);
    x2 = __expf(x2 - m);
    x3 = __expf(x3 - m);
    const float inv = __frcp_rn(x0 + x1 + x2 + x3);
    x0 *= inv; x1 *= inv; x2 *= inv; x3 *= inv;

    float4 o;
    o.x = x0 * e0.x + x1 * e1.x + x2 * e2.x + x3 * e3.x;
    o.y = x0 * e0.y + x1 * e1.y + x2 * e2.y + x3 * e3.y;
    o.z = x0 * e0.z + x1 * e1.z + x2 * e2.z + x3 * e3.z;
    o.w = x0 * e0.w + x1 * e1.w + x2 * e2.w + x3 * e3.w;

    float4* op = (float4*)(out + ((size_t)t * B + b) * DD);
    op[lane] = o;
}

extern "C" void kernel_launch(void* const* d_in, const int* in_sizes, int n_in,
                              void* d_out, int out_size, void* d_ws, size_t ws_size,
                              hipStream_t stream) {
    const float* h_center = (const float*)d_in[0];  // (T,B,D)
    const float* h_neigh  = (const float*)d_in[1];  // (T,T,B,D)
    const float* att_w    = (const float*)d_in[2];  // (T,2D)
    const float* att_b    = (const float*)d_in[3];  // (T,)
    float* out = (float*)d_out;

    int B = in_sizes[0] / (TT * DD);                // 100000
    dim3 grid((B + 7) / 8, TT);                     // 8 rows per 256-thread block
    attconv_kernel<<<grid, 256, 0, stream>>>(h_center, h_neigh, att_w, att_b, out, B);
}